// Round 2
// baseline (393.971 us; speedup 1.0000x reference)
//
#include <hip/hip_runtime.h>

typedef __attribute__((ext_vector_type(8))) short short8;
typedef __attribute__((ext_vector_type(4))) float f32x4;

#define NB 8
#define NP 64
#define NS 256
#define ND 256
#define LSTR 264   // LDS row stride (bf16 elems): 528 B, 16B-aligned, 2-way bank alias only

// round-to-nearest-even fp32 -> bf16 bits
__device__ __forceinline__ unsigned short f2bf(float f) {
    unsigned int u = __float_as_uint(f);
    u = (u + 0x7FFFu + ((u >> 16) & 1u)) >> 16;
    return (unsigned short)u;
}

// K1: one wg per (b,p). Full X[b,p] staged bf16 in LDS once; 4 s-blocks of the
// scores GEMM run out of LDS. red[s] = (1/16) sum_t w[p,s,t] * (X X^T)[s,t].
// Sx (fp32) reduced during staging; Sxx comes free from the score diagonal.
__global__ __launch_bounds__(256, 1) void k1_gemm_red(
    const float* __restrict__ x, const float* __restrict__ w,
    float* __restrict__ red, float* __restrict__ Sx, float* __restrict__ Sxx)
{
    __shared__ unsigned short Xl[NS * LSTR];   // 135168 B
    __shared__ float red_l[4][NS];             // 4096 B

    const int t    = threadIdx.x;
    const int lane = t & 63;
    const int wv   = t >> 6;                   // wave 0..3 -> t-cols [64*wv, 64*wv+64)
    const int p    = blockIdx.x & 63;
    const int b    = blockIdx.x >> 6;

    const float* xb      = x + (size_t)(b * NP + p) * (NS * ND);
    const size_t rowbase = (size_t)(b * NP + p) * NS;

    // ---- stage X fp32->bf16 into LDS; fp32 row sums (Sx) on the fly ----
    // iter i: wave wv owns row 4i+wv; lane covers floats 4*lane..4*lane+3 (coalesced 1KB/wave)
    #pragma unroll 4
    for (int i = 0; i < 64; ++i) {
        const int row = 4 * i + wv;
        f32x4 v = *reinterpret_cast<const f32x4*>(xb + row * ND + 4 * lane);
        float a = (v.x + v.y) + (v.z + v.w);
        #pragma unroll
        for (int off = 1; off < 64; off <<= 1) a += __shfl_xor(a, off, 64);
        if (lane == 0) Sx[rowbase + row] = a;
        unsigned long long pk =
              (unsigned long long)f2bf(v.x)
            | ((unsigned long long)f2bf(v.y) << 16)
            | ((unsigned long long)f2bf(v.z) << 32)
            | ((unsigned long long)f2bf(v.w) << 48);
        *reinterpret_cast<unsigned long long*>(&Xl[row * LSTR + 4 * lane]) = pk;
    }
    __syncthreads();

    const int qd = lane >> 4;
    const int c  = lane & 15;
    const float* wp = w + (size_t)p * (NS * NS);

    for (int sb = 0; sb < 4; ++sb) {
        f32x4 acc[4][4] = {};                  // 64x64 per wave: 4x4 tiles of 16x16
        #pragma unroll
        for (int k0 = 0; k0 < ND; k0 += 32) {
            const int kof = k0 + qd * 8;
            short8 afr[4], bfr[4];
            #pragma unroll
            for (int i = 0; i < 4; ++i)
                afr[i] = *reinterpret_cast<const short8*>(
                    &Xl[(64 * sb + 16 * i + c) * LSTR + kof]);
            #pragma unroll
            for (int j = 0; j < 4; ++j)
                bfr[j] = *reinterpret_cast<const short8*>(
                    &Xl[(64 * wv + 16 * j + c) * LSTR + kof]);
            #pragma unroll
            for (int i = 0; i < 4; ++i)
                #pragma unroll
                for (int j = 0; j < 4; ++j)
                    acc[i][j] = __builtin_amdgcn_mfma_f32_16x16x32_bf16(
                        afr[i], bfr[j], acc[i][j], 0, 0, 0);
        }

        // Sxx = diagonal of X X^T (unscaled scores): tile i==j, 4*qd+r == c
        if (wv == sb && qd == (c >> 2)) {
            #pragma unroll
            for (int i = 0; i < 4; ++i)
                Sxx[rowbase + 64 * sb + 16 * i + c] = acc[i][i][c & 3];
        }

        // weighted reduction over t: C layout col=lane&15, row=4*qd+reg
        #pragma unroll
        for (int i = 0; i < 4; ++i) {
            #pragma unroll
            for (int r = 0; r < 4; ++r) {
                const int rl = 16 * i + 4 * qd + r;       // local row in [0,64)
                const float* wrow = wp + (size_t)(64 * sb + rl) * NS + 64 * wv + c;
                float s = acc[i][0][r] * wrow[0]
                        + acc[i][1][r] * wrow[16]
                        + acc[i][2][r] * wrow[32]
                        + acc[i][3][r] * wrow[48];
                #pragma unroll
                for (int off = 1; off < 16; off <<= 1)
                    s += __shfl_xor(s, off, 64);
                if (c == 0) red_l[wv][64 * sb + rl] = s;  // wave-private region, no sync needed
            }
        }
    }
    __syncthreads();
    red[rowbase + t] =
        (red_l[0][t] + red_l[1][t] + red_l[2][t] + red_l[3][t]) * 0.0625f;
}

// K2: per-channel BN stats -> scale/bias
__global__ __launch_bounds__(256) void k2_stats(
    const float* __restrict__ red, const float* __restrict__ Sx,
    const float* __restrict__ Sxx, const float* __restrict__ gamma,
    const float* __restrict__ beta, float* __restrict__ sb)
{
    __shared__ float l1[256], l2[256];
    const int p = blockIdx.x;
    const int t = threadIdx.x;
    float sy = 0.f, syy = 0.f;
    for (int n = t; n < NB * NS; n += 256) {
        int bb = n >> 8, s = n & 255;
        size_t idx = (size_t)(bb * NP + p) * NS + s;
        float r = red[idx], a = Sx[idx], q = Sxx[idx];
        sy  += a + 256.f * r;
        syy += q + 2.f * r * a + 256.f * r * r;
    }
    l1[t] = sy; l2[t] = syy;
    __syncthreads();
    for (int off = 128; off > 0; off >>= 1) {
        if (t < off) { l1[t] += l1[t + off]; l2[t] += l2[t + off]; }
        __syncthreads();
    }
    if (t == 0) {
        const float invN = 1.f / (float)(NB * NS * ND);
        float mean = l1[0] * invN;
        float var  = l2[0] * invN - mean * mean;
        float sc   = gamma[p] * rsqrtf(var + 1e-5f);
        sb[p]      = sc;
        sb[64 + p] = beta[p] - mean * sc;
    }
}

// K3: out = (x + red) * scale[p] + bias[p]; 4 float4 per thread for MLP
__global__ __launch_bounds__(256) void k3_norm(
    const float* __restrict__ x, const float* __restrict__ red,
    const float* __restrict__ sb, float* __restrict__ out)
{
    const size_t f0 = (size_t)blockIdx.x * 1024 + threadIdx.x;
    #pragma unroll
    for (int k = 0; k < 4; ++k) {
        const size_t f = f0 + (size_t)k * 256;            // float4 index
        f32x4 v = reinterpret_cast<const f32x4*>(x)[f];
        const float r  = red[f >> 6];                     // row = elem>>8 = f>>6
        const int   pp = (int)((f >> 14) & 63);
        v = (v + r) * sb[pp] + sb[64 + pp];
        reinterpret_cast<f32x4*>(out)[f] = v;
    }
}

extern "C" void kernel_launch(void* const* d_in, const int* in_sizes, int n_in,
                              void* d_out, int out_size, void* d_ws, size_t ws_size,
                              hipStream_t stream)
{
    const float* x     = (const float*)d_in[0];
    const float* w     = (const float*)d_in[1];
    const float* gamma = (const float*)d_in[2];
    const float* beta  = (const float*)d_in[3];
    float* out = (float*)d_out;

    float* red = (float*)d_ws;                  // NB*NP*NS floats
    float* Sx  = red + (size_t)NB * NP * NS;
    float* Sxx = Sx  + (size_t)NB * NP * NS;
    float* sb  = Sxx + (size_t)NB * NP * NS;    // 128 floats (scale, bias)

    hipLaunchKernelGGL(k1_gemm_red, dim3(NB * NP), dim3(256), 0, stream,
                       x, w, red, Sx, Sxx);
    hipLaunchKernelGGL(k2_stats, dim3(NP), dim3(256), 0, stream,
                       red, Sx, Sxx, gamma, beta, sb);
    hipLaunchKernelGGL(k3_norm, dim3((NB * NP * NS * ND) / (16 * 256)), dim3(256),
                       0, stream, x, red, sb, out);
}

// Round 3
// 288.998 us; speedup vs baseline: 1.3632x; 1.3632x over previous
//
#include <hip/hip_runtime.h>

typedef __attribute__((ext_vector_type(8))) short short8;
typedef __attribute__((ext_vector_type(4))) float f32x4;

#define NB 8
#define NP 64
#define NS 256
#define ND 256
#define LSTR 264   // LDS row stride (bf16): 528 B, 16B-aligned, 2-way bank alias only (free)

// round-to-nearest-even fp32 -> bf16 bits
__device__ __forceinline__ unsigned short f2bf(float f) {
    unsigned int u = __float_as_uint(f);
    u = (u + 0x7FFFu + ((u >> 16) & 1u)) >> 16;
    return (unsigned short)u;
}

// K1: one wg (1024 thr = 16 waves) per (b,p). Full X[b,p] bf16 in LDS; wave w
// owns score tile (ib=w>>2, jb=w&3) of the 256x256 scores = X X^T.
// red[s] = (1/16) sum_t w[p,s,t]*scores[s,t]; Sx during staging; Sxx = diag.
__global__ __launch_bounds__(1024, 4) void k1_gemm_red(
    const float* __restrict__ x, const float* __restrict__ w,
    float* __restrict__ red, float* __restrict__ Sx, float* __restrict__ Sxx)
{
    __shared__ unsigned short Xl[NS * LSTR];   // 135168 B
    __shared__ float red_l[4][NS];             // 4096 B

    const int t    = threadIdx.x;
    const int lane = t & 63;
    const int wv   = t >> 6;                   // 0..15
    const int ib   = wv >> 2;                  // row block of this wave's tile
    const int jb   = wv & 3;                   // col block
    const int p    = blockIdx.x & 63;
    const int b    = blockIdx.x >> 6;

    const float* xb      = x + (size_t)(b * NP + p) * (NS * ND);
    const size_t rowbase = (size_t)(b * NP + p) * NS;

    // ---- stage X fp32->bf16; wave w loads full row 16*i+w (coalesced 1KB/wave) ----
    #pragma unroll 4
    for (int i = 0; i < 16; ++i) {
        const int row = 16 * i + wv;
        f32x4 v = *reinterpret_cast<const f32x4*>(xb + row * ND + 4 * lane);
        float a = (v.x + v.y) + (v.z + v.w);
        #pragma unroll
        for (int off = 1; off < 64; off <<= 1) a += __shfl_xor(a, off, 64);
        if (lane == 0) Sx[rowbase + row] = a;
        unsigned long long pk =
              (unsigned long long)f2bf(v.x)
            | ((unsigned long long)f2bf(v.y) << 16)
            | ((unsigned long long)f2bf(v.z) << 32)
            | ((unsigned long long)f2bf(v.w) << 48);
        *reinterpret_cast<unsigned long long*>(&Xl[row * LSTR + 4 * lane]) = pk;
    }
    __syncthreads();

    const int qd = lane >> 4;
    const int c  = lane & 15;

    // ---- 64x64 tile GEMM out of LDS: 4x4 grid of 16x16x32 MFMAs, K=256 ----
    f32x4 acc[4][4] = {};
    #pragma unroll 2
    for (int k0 = 0; k0 < ND; k0 += 32) {
        const int kof = k0 + qd * 8;
        short8 afr[4], bfr[4];
        #pragma unroll
        for (int i = 0; i < 4; ++i)
            afr[i] = *reinterpret_cast<const short8*>(
                &Xl[(64 * ib + 16 * i + c) * LSTR + kof]);
        #pragma unroll
        for (int j = 0; j < 4; ++j)
            bfr[j] = *reinterpret_cast<const short8*>(
                &Xl[(64 * jb + 16 * j + c) * LSTR + kof]);
        #pragma unroll
        for (int i = 0; i < 4; ++i)
            #pragma unroll
            for (int j = 0; j < 4; ++j)
                acc[i][j] = __builtin_amdgcn_mfma_f32_16x16x32_bf16(
                    afr[i], bfr[j], acc[i][j], 0, 0, 0);
    }

    // ---- Sxx = diag of X X^T: tiles with ib==jb, element needs 16i+4qd+r == 16j+c ----
    if (ib == jb && qd == (c >> 2)) {
        #pragma unroll
        for (int i = 0; i < 4; ++i)
            Sxx[rowbase + 64 * ib + 16 * i + c] = acc[i][i][c & 3];
    }

    // ---- weighted reduction over this tile's 64 cols; C layout col=c, row=4qd+reg ----
    const float* wp = w + (size_t)p * (NS * NS);
    #pragma unroll
    for (int i = 0; i < 4; ++i) {
        #pragma unroll
        for (int r = 0; r < 4; ++r) {
            const int rl = 16 * i + 4 * qd + r;       // local row in [0,64)
            const float* wrow = wp + (size_t)(64 * ib + rl) * NS + 64 * jb + c;
            float s = acc[i][0][r] * wrow[0]
                    + acc[i][1][r] * wrow[16]
                    + acc[i][2][r] * wrow[32]
                    + acc[i][3][r] * wrow[48];
            #pragma unroll
            for (int off = 1; off < 16; off <<= 1)
                s += __shfl_xor(s, off, 64);
            if (c == 0) red_l[jb][64 * ib + rl] = s;  // disjoint per (jb,row): no race
        }
    }
    __syncthreads();
    if (t < NS)
        red[rowbase + t] =
            (red_l[0][t] + red_l[1][t] + red_l[2][t] + red_l[3][t]) * 0.0625f;
}

// K2: per-channel BN stats -> scale/bias
__global__ __launch_bounds__(256) void k2_stats(
    const float* __restrict__ red, const float* __restrict__ Sx,
    const float* __restrict__ Sxx, const float* __restrict__ gamma,
    const float* __restrict__ beta, float* __restrict__ sb)
{
    __shared__ float l1[256], l2[256];
    const int p = blockIdx.x;
    const int t = threadIdx.x;
    float sy = 0.f, syy = 0.f;
    for (int n = t; n < NB * NS; n += 256) {
        int bb = n >> 8, s = n & 255;
        size_t idx = (size_t)(bb * NP + p) * NS + s;
        float r = red[idx], a = Sx[idx], q = Sxx[idx];
        sy  += a + 256.f * r;
        syy += q + 2.f * r * a + 256.f * r * r;
    }
    l1[t] = sy; l2[t] = syy;
    __syncthreads();
    for (int off = 128; off > 0; off >>= 1) {
        if (t < off) { l1[t] += l1[t + off]; l2[t] += l2[t + off]; }
        __syncthreads();
    }
    if (t == 0) {
        const float invN = 1.f / (float)(NB * NS * ND);
        float mean = l1[0] * invN;
        float var  = l2[0] * invN - mean * mean;
        float sc   = gamma[p] * rsqrtf(var + 1e-5f);
        sb[p]      = sc;
        sb[64 + p] = beta[p] - mean * sc;
    }
}

// K3: out = (x + red) * scale[p] + bias[p]; 4 float4/thread; nt stores keep L3 for x
__global__ __launch_bounds__(256) void k3_norm(
    const float* __restrict__ x, const float* __restrict__ red,
    const float* __restrict__ sb, float* __restrict__ out)
{
    const size_t f0 = (size_t)blockIdx.x * 1024 + threadIdx.x;
    #pragma unroll
    for (int k = 0; k < 4; ++k) {
        const size_t f = f0 + (size_t)k * 256;            // float4 index
        f32x4 v = reinterpret_cast<const f32x4*>(x)[f];
        const float r  = red[f >> 6];                     // row = elem>>8 = f>>6
        const int   pp = (int)((f >> 14) & 63);
        v = (v + r) * sb[pp] + sb[64 + pp];
        __builtin_nontemporal_store(v, reinterpret_cast<f32x4*>(out) + f);
    }
}

extern "C" void kernel_launch(void* const* d_in, const int* in_sizes, int n_in,
                              void* d_out, int out_size, void* d_ws, size_t ws_size,
                              hipStream_t stream)
{
    const float* x     = (const float*)d_in[0];
    const float* w     = (const float*)d_in[1];
    const float* gamma = (const float*)d_in[2];
    const float* beta  = (const float*)d_in[3];
    float* out = (float*)d_out;

    float* red = (float*)d_ws;                  // NB*NP*NS floats
    float* Sx  = red + (size_t)NB * NP * NS;
    float* Sxx = Sx  + (size_t)NB * NP * NS;
    float* sb  = Sxx + (size_t)NB * NP * NS;    // 128 floats (scale, bias)

    hipLaunchKernelGGL(k1_gemm_red, dim3(NB * NP), dim3(1024), 0, stream,
                       x, w, red, Sx, Sxx);
    hipLaunchKernelGGL(k2_stats, dim3(NP), dim3(256), 0, stream,
                       red, Sx, Sxx, gamma, beta, sb);
    hipLaunchKernelGGL(k3_norm, dim3((NB * NP * NS * ND) / (16 * 256)), dim3(256),
                       0, stream, x, red, sb, out);
}